// Round 10
// baseline (1761.992 us; speedup 1.0000x reference)
//
#include <hip/hip_runtime.h>
#include <cstdint>
#include <cstddef>

// Problem constants
#define BATCHN 32
#define LSEQ   196     // (224/16)^2
#define DMODEL 512
#define DINNER 1024    // 2*DM
#define PDIM   768     // 3*16*16
#define NSTATE 16
#define RRANK  32
#define NLAYER 6

typedef __bf16 bf16_t;
typedef __bf16 bf16x8 __attribute__((ext_vector_type(8)));
typedef float  f32x4  __attribute__((ext_vector_type(4)));

// async global->LDS, 16B per lane: lane i lands at lds + i*16 bytes.
__device__ __forceinline__ void gl_lds16(const bf16_t* g, bf16_t* l) {
    __builtin_amdgcn_global_load_lds(
        (const __attribute__((address_space(1))) void*)g,
        (__attribute__((address_space(3))) void*)l, 16, 0, 0);
}

// ---------------------------------------------------------------------------
// Split fp32 -> (hi, lo) bf16 pair.  x ~= hi + lo to ~2^-16 relative.
// ---------------------------------------------------------------------------
__global__ __launch_bounds__(256) void split_kernel(
    const float* __restrict__ src, bf16_t* __restrict__ hi,
    bf16_t* __restrict__ lo, int n)
{
    int i = blockIdx.x * 256 + threadIdx.x;
    if (i < n) {
        float x = src[i];
        bf16_t h = (bf16_t)x;
        hi[i] = h;
        lo[i] = (bf16_t)(x - (float)h);
    }
}

// ---------------------------------------------------------------------------
// bf16x3 split-precision MFMA GEMM:  C = A[M,K] @ W[N,K]^T (+bias)
// R10: A-fragments load DIRECTLY global->VGPR (16B contiguous, exact MFMA
// A-layout, L2-hot) — A never touches LDS.  Only B is staged via gl_lds,
// double-buffered.  This halves LDS traffic (R9 model: 96KB/iter/block at
// 128B/cyc = 750cyc vs 230cyc of MFMA -> 27% MfmaUtil observed; now 48KB
// -> ~375cyc -> ~60% ceiling).  One barrier per K-iter; next A-frags
// prefetch into regs during the current iter (drained by the barrier).
// Split-K via gridDim.z: partials to C + z*M*N (summed by the next LN).
// Requires M%128==0, N%128==0, (K/gridDim.z)%32==0.
// ---------------------------------------------------------------------------
__global__ __launch_bounds__(256) void gemm_mfma3(
    const bf16_t* __restrict__ Ah, const bf16_t* __restrict__ Al,
    const bf16_t* __restrict__ Wh, const bf16_t* __restrict__ Wl,
    float* __restrict__ C, const float* __restrict__ bias,
    int M, int N, int K)
{
    __shared__ bf16_t sBh[2][128 * 32];
    __shared__ bf16_t sBl[2][128 * 32];

    const int bm = blockIdx.y * 128;
    const int bn = blockIdx.x * 128;
    const int kchunk = K / gridDim.z;
    const int kb = blockIdx.z * kchunk;
    C += (size_t)blockIdx.z * M * N;

    const int tid  = threadIdx.x;
    const int lane = tid & 63;
    const int w    = tid >> 6;
    const int wm   = (w & 1) * 64;
    const int wn   = (w >> 1) * 64;

    // B staging (gl_lds 16B/lane): wave w covers rows [w*32, w*32+32),
    // source chunk XOR-swizzled so swizzled fragment reads are conflict-free.
    const int lrow = lane >> 2;
    const int cg8  = ((lane & 3) ^ ((lane >> 3) & 3)) * 8;
    const size_t brow = (size_t)(bn + w * 32 + lrow) * K + cg8;
    const int llo = w * 1024;

    // fragment geometry
    const int fr  = lane & 15;
    const int fsw = ((lane >> 4) ^ ((lane >> 1) & 3)) * 8;  // B (swizzled LDS)
    const int fc  = (lane >> 4) * 8;                        // A (direct global)
    const size_t arow0 = (size_t)(bm + wm + fr) * K + fc;

    f32x4 acc[4][4] = {};

    // prologue: stage B tile 0, load A frags 0
    #pragma unroll
    for (int j = 0; j < 2; ++j) {
        gl_lds16(Wh + brow + (size_t)j * 16 * K + kb, &sBh[0][llo + j * 512]);
        gl_lds16(Wl + brow + (size_t)j * 16 * K + kb, &sBl[0][llo + j * 512]);
    }
    bf16x8 afh[4], afl[4];
    #pragma unroll
    for (int mt = 0; mt < 4; ++mt) {
        afh[mt] = *(const bf16x8*)(Ah + arow0 + (size_t)mt * 16 * K + kb);
        afl[mt] = *(const bf16x8*)(Al + arow0 + (size_t)mt * 16 * K + kb);
    }

    const int kiter = kchunk / 32;
    for (int ki = 0; ki < kiter; ++ki) {
        const int buf = ki & 1;
        __syncthreads();   // B[ki] staged (vmcnt0 drain also retires A[ki])

        // prefetch next tile: A -> regs, B -> other LDS buffer
        bf16x8 nfh[4], nfl[4];
        if (ki + 1 < kiter) {
            const int k0 = kb + (ki + 1) * 32;
            #pragma unroll
            for (int mt = 0; mt < 4; ++mt) {
                nfh[mt] = *(const bf16x8*)(Ah + arow0 + (size_t)mt * 16 * K + k0);
                nfl[mt] = *(const bf16x8*)(Al + arow0 + (size_t)mt * 16 * K + k0);
            }
            #pragma unroll
            for (int j = 0; j < 2; ++j) {
                gl_lds16(Wh + brow + (size_t)j * 16 * K + k0,
                         &sBh[buf ^ 1][llo + j * 512]);
                gl_lds16(Wl + brow + (size_t)j * 16 * K + k0,
                         &sBl[buf ^ 1][llo + j * 512]);
            }
        }

        // MFMA sweep; B fragments read inline from the stable sB[buf]
        #pragma unroll
        for (int nt = 0; nt < 4; ++nt) {
            const int r = wn + nt * 16 + fr;
            bf16x8 bfh = *(const bf16x8*)&sBh[buf][r * 32 + fsw];
            bf16x8 bfl = *(const bf16x8*)&sBl[buf][r * 32 + fsw];
            #pragma unroll
            for (int mt = 0; mt < 4; ++mt)
                acc[mt][nt] = __builtin_amdgcn_mfma_f32_16x16x32_bf16(
                    afh[mt], bfh, acc[mt][nt], 0, 0, 0);
            #pragma unroll
            for (int mt = 0; mt < 4; ++mt)
                acc[mt][nt] = __builtin_amdgcn_mfma_f32_16x16x32_bf16(
                    afh[mt], bfl, acc[mt][nt], 0, 0, 0);
            #pragma unroll
            for (int mt = 0; mt < 4; ++mt)
                acc[mt][nt] = __builtin_amdgcn_mfma_f32_16x16x32_bf16(
                    afl[mt], bfh, acc[mt][nt], 0, 0, 0);
        }

        if (ki + 1 < kiter) {
            #pragma unroll
            for (int mt = 0; mt < 4; ++mt) {
                afh[mt] = nfh[mt]; afl[mt] = nfl[mt];
            }
        }
    }

    // epilogue: C/D layout col=lane&15, row=(lane>>4)*4+reg  [m89-verified]
    const int cr = (lane >> 4) * 4;
    const int cc = lane & 15;
    #pragma unroll
    for (int nt = 0; nt < 4; ++nt) {
        const int n = bn + wn + nt * 16 + cc;
        const float bv = bias ? bias[n] : 0.f;
        #pragma unroll
        for (int mt = 0; mt < 4; ++mt) {
            const int m0 = bm + wm + mt * 16 + cr;
            #pragma unroll
            for (int r = 0; r < 4; ++r)
                C[(size_t)(m0 + r) * N + n] = acc[mt][nt][r] + bv;
        }
    }
}

// ---------------------------------------------------------------------------
// fp32 vector NT GEMM (used for dt_proj: K=32).  C = A@W^T (+bias)(+softplus)
// ---------------------------------------------------------------------------
__global__ __launch_bounds__(256) void gemm_nt(
    const float* __restrict__ A, int lda,
    const float* __restrict__ W,
    float* __restrict__ C, int ldc,
    const float* __restrict__ bias,
    int M, int N, int K, int act)
{
    __shared__ float As[16][64];
    __shared__ float Ws[16][64];
    const int bm = blockIdx.y * 64;
    const int bn = blockIdx.x * 64;
    const int tid = threadIdx.x;
    const int tx = tid & 15;
    const int ty = tid >> 4;
    const int r   = tid >> 2;
    const int kk4 = (tid & 3) << 2;

    float acc[4][4];
    #pragma unroll
    for (int i = 0; i < 4; ++i)
        #pragma unroll
        for (int j = 0; j < 4; ++j) acc[i][j] = 0.f;

    for (int k0 = 0; k0 < K; k0 += 16) {
        float4 va = *(const float4*)(A + (size_t)(bm + r) * lda + k0 + kk4);
        float4 vw = *(const float4*)(W + (size_t)(bn + r) * K   + k0 + kk4);
        __syncthreads();
        As[kk4 + 0][r] = va.x; As[kk4 + 1][r] = va.y;
        As[kk4 + 2][r] = va.z; As[kk4 + 3][r] = va.w;
        Ws[kk4 + 0][r] = vw.x; Ws[kk4 + 1][r] = vw.y;
        Ws[kk4 + 2][r] = vw.z; Ws[kk4 + 3][r] = vw.w;
        __syncthreads();
        #pragma unroll
        for (int kk = 0; kk < 16; ++kk) {
            float4 a = *(const float4*)&As[kk][ty << 2];
            float4 b = *(const float4*)&Ws[kk][tx << 2];
            acc[0][0] += a.x * b.x; acc[0][1] += a.x * b.y;
            acc[0][2] += a.x * b.z; acc[0][3] += a.x * b.w;
            acc[1][0] += a.y * b.x; acc[1][1] += a.y * b.y;
            acc[1][2] += a.y * b.z; acc[1][3] += a.y * b.w;
            acc[2][0] += a.z * b.x; acc[2][1] += a.z * b.y;
            acc[2][2] += a.z * b.z; acc[2][3] += a.z * b.w;
            acc[3][0] += a.w * b.x; acc[3][1] += a.w * b.y;
            acc[3][2] += a.w * b.z; acc[3][3] += a.w * b.w;
        }
    }

    #pragma unroll
    for (int i = 0; i < 4; ++i) {
        const int m = bm + (ty << 2) + i;
        #pragma unroll
        for (int j = 0; j < 4; ++j) {
            const int n = bn + (tx << 2) + j;
            float v = acc[i][j];
            if (bias) v += bias[n];
            if (act == 1) {
                v = (v > 20.f) ? v : log1pf(expf(v));
            }
            C[(size_t)m * ldc + n] = v;
        }
    }
}

// ---------------------------------------------------------------------------
// FUSED conv+silu+x_proj split-K.  Computes xc = silu(causal depthwise
// conv(xs)) inline while staging the A-tile, writes xc once (for the scan),
// and accumulates the x_proj partial GEMM (N=64).  grid=(1, M/64, NSPLIT).
// ---------------------------------------------------------------------------
__global__ __launch_bounds__(256) void conv_xproj_kernel(
    const float* __restrict__ xz, const float* __restrict__ cw,
    const float* __restrict__ cb, const float* __restrict__ xpW,
    float* __restrict__ xc, float* __restrict__ Cpart,
    int kchunk)
{
    __shared__ float As[16][64];
    __shared__ float Ws[16][64];
    __shared__ float scw[128 * 4 + 128];   // conv w (128 ch x 4) + bias (128)

    const int bm = blockIdx.y * 64;
    const int kb = blockIdx.z * kchunk;
    Cpart += (size_t)blockIdx.z * (BATCHN * LSEQ) * 64;

    const int tid = threadIdx.x;
    if (tid < 128) {
        *(float4*)&scw[tid * 4] = *(const float4*)(cw + (size_t)(kb + tid) * 4);
        scw[512 + tid] = cb[kb + tid];
    }
    __syncthreads();

    const int tx = tid & 15;
    const int ty = tid >> 4;
    const int r   = tid >> 2;
    const int kk4 = (tid & 3) << 2;
    const int bl  = bm + r;          // global token row
    const int l   = bl % LSEQ;       // position within batch
    const float* xrow = xz + ((size_t)bl << 11);   // xs row (stride 2048)

    float acc[4][4];
    #pragma unroll
    for (int i = 0; i < 4; ++i)
        #pragma unroll
        for (int j = 0; j < 4; ++j) acc[i][j] = 0.f;

    for (int k0 = 0; k0 < kchunk; k0 += 16) {
        const int cl = k0 + kk4;       // channel offset within split
        const int c  = kb + cl;        // global channel
        // --- conv + silu for 4 channels at row bl ---
        float4 va = *(const float4*)&scw[512 + cl];
        #pragma unroll
        for (int kk = 0; kk < 4; ++kk) {
            int ls = l + kk - 3;
            if (ls >= 0) {
                float4 xv = *(const float4*)(xrow + ((ptrdiff_t)(kk - 3) << 11) + c);
                va.x += scw[(cl + 0) * 4 + kk] * xv.x;
                va.y += scw[(cl + 1) * 4 + kk] * xv.y;
                va.z += scw[(cl + 2) * 4 + kk] * xv.z;
                va.w += scw[(cl + 3) * 4 + kk] * xv.w;
            }
        }
        va.x = va.x * __builtin_amdgcn_rcpf(1.f + __expf(-va.x));
        va.y = va.y * __builtin_amdgcn_rcpf(1.f + __expf(-va.y));
        va.z = va.z * __builtin_amdgcn_rcpf(1.f + __expf(-va.z));
        va.w = va.w * __builtin_amdgcn_rcpf(1.f + __expf(-va.w));
        *(float4*)(xc + ((size_t)bl << 10) + c) = va;

        float4 vw = *(const float4*)(xpW + (size_t)r * DINNER + c);
        __syncthreads();
        As[kk4 + 0][r] = va.x; As[kk4 + 1][r] = va.y;
        As[kk4 + 2][r] = va.z; As[kk4 + 3][r] = va.w;
        Ws[kk4 + 0][r] = vw.x; Ws[kk4 + 1][r] = vw.y;
        Ws[kk4 + 2][r] = vw.z; Ws[kk4 + 3][r] = vw.w;
        __syncthreads();
        #pragma unroll
        for (int kk = 0; kk < 16; ++kk) {
            float4 a = *(const float4*)&As[kk][ty << 2];
            float4 b = *(const float4*)&Ws[kk][tx << 2];
            acc[0][0] += a.x * b.x; acc[0][1] += a.x * b.y;
            acc[0][2] += a.x * b.z; acc[0][3] += a.x * b.w;
            acc[1][0] += a.y * b.x; acc[1][1] += a.y * b.y;
            acc[1][2] += a.y * b.z; acc[1][3] += a.y * b.w;
            acc[2][0] += a.z * b.x; acc[2][1] += a.z * b.y;
            acc[2][2] += a.z * b.z; acc[2][3] += a.z * b.w;
            acc[3][0] += a.w * b.x; acc[3][1] += a.w * b.y;
            acc[3][2] += a.w * b.z; acc[3][3] += a.w * b.w;
        }
    }

    #pragma unroll
    for (int i = 0; i < 4; ++i) {
        const int m = bm + (ty << 2) + i;
        #pragma unroll
        for (int j = 0; j < 4; ++j) {
            const int n = (tx << 2) + j;
            Cpart[(size_t)m * 64 + n] = acc[i][j];
        }
    }
}

__global__ __launch_bounds__(256) void reduce_splitk(
    const float* __restrict__ part, float* __restrict__ out, int n, int nsplit)
{
    int i = blockIdx.x * 256 + threadIdx.x;
    if (i < n) {
        float s = 0.f;
        for (int j = 0; j < nsplit; ++j) s += part[(size_t)j * n + i];
        out[i] = s;
    }
}

// ---------------------------------------------------------------------------
// Patchify: x (B,3,224,224) -> tp (B, 196, 768), pd = c*256 + p1*16 + p2
// ---------------------------------------------------------------------------
__global__ __launch_bounds__(256) void patchify_kernel(
    const float* __restrict__ x, float* __restrict__ tp)
{
    int idx = blockIdx.x * 256 + threadIdx.x;   // B*L*PD = 4,816,896
    int pd = idx % PDIM;
    int bl = idx / PDIM;
    int l = bl % LSEQ, b = bl / LSEQ;
    int c = pd >> 8, rem = pd & 255, p1 = rem >> 4, p2 = rem & 15;
    int gh = l / 14, gw = l % 14;
    int hh = gh * 16 + p1, ww = gw * 16 + p2;
    tp[idx] = x[(((size_t)b * 3 + c) * 224 + hh) * 224 + ww];
}

// ---------------------------------------------------------------------------
// LayerNorm over last dim W (512 or 768). Optional second input (split-K
// partial sum), optional residual, optional fp32 out, optional bf16 hi/lo.
// ---------------------------------------------------------------------------
__global__ __launch_bounds__(256) void ln_kernel(
    const float* __restrict__ in, const float* __restrict__ in2,
    const float* __restrict__ res,
    const float* __restrict__ g, const float* __restrict__ bt,
    float* __restrict__ out, bf16_t* __restrict__ hi,
    bf16_t* __restrict__ lo, int W)
{
    __shared__ float red[4];
    const int row = blockIdx.x;
    const size_t base = (size_t)row * W;
    const int nper = W >> 8;      // 2 or 3
    float vals[3];
    float s = 0.f;
    for (int j = 0; j < nper; ++j) {
        int c = (j << 8) + threadIdx.x;
        float v = in[base + c];
        if (in2) v += in2[base + c];
        if (res) v += res[base + c];
        vals[j] = v;
        s += v;
    }
    int lane = threadIdx.x & 63, wid = threadIdx.x >> 6;
    #pragma unroll
    for (int o = 32; o > 0; o >>= 1) s += __shfl_down(s, o);
    if (lane == 0) red[wid] = s;
    __syncthreads();
    float mu = (red[0] + red[1] + red[2] + red[3]) / (float)W;
    __syncthreads();
    float vs = 0.f;
    for (int j = 0; j < nper; ++j) { float d = vals[j] - mu; vs += d * d; }
    #pragma unroll
    for (int o = 32; o > 0; o >>= 1) vs += __shfl_down(vs, o);
    if (lane == 0) red[wid] = vs;
    __syncthreads();
    float var = (red[0] + red[1] + red[2] + red[3]) / (float)W;
    float rstd = rsqrtf(var + 1e-5f);
    for (int j = 0; j < nper; ++j) {
        int c = (j << 8) + threadIdx.x;
        float v = (vals[j] - mu) * rstd * g[c] + bt[c];
        if (out) out[base + c] = v;
        if (hi) {
            bf16_t h = (bf16_t)v;
            hi[base + c] = h;
            lo[base + c] = (bf16_t)(v - (float)h);
        }
    }
}

// ---------------------------------------------------------------------------
// quad broadcast: all 4 lanes of a quad get lane J's value (DPP quad_perm).
// ---------------------------------------------------------------------------
template<int J>
__device__ __forceinline__ float qbcast(float v) {
    constexpr int ctrl = J | (J << 2) | (J << 4) | (J << 6);
    return __int_as_float(__builtin_amdgcn_mov_dpp(
        __float_as_int(v), ctrl, 0xF, 0xF, true));
}

// ---------------------------------------------------------------------------
// Selective scan v6: state-parallel, group-4 steps, wave-private LDS staging
// of shared B/C rows, depth-2 scalar pipeline, group-batched stores.
// ---------------------------------------------------------------------------
__global__ __launch_bounds__(256, 1) void scan_kernel(
    const float* __restrict__ xc, const float* __restrict__ dt,
    const float* __restrict__ xdbl, const float* __restrict__ A_log,
    const float* __restrict__ Dv, const float* __restrict__ xz,
    bf16_t* __restrict__ yh, bf16_t* __restrict__ yl)
{
    __shared__ float sBC[4][2][256];   // [wave][buf][4 steps x 64 floats]

    const int b    = blockIdx.y;
    const int tid  = threadIdx.x;
    const int lane = tid & 63;
    const int w    = tid >> 6;
    const int q    = tid >> 2;        // channel within block (0..63)
    const int sub  = tid & 3;         // state group: states [4*sub, 4*sub+4)
    const int d    = blockIdx.x * 64 + q;

    float A2[4], h[4];
    #pragma unroll
    for (int n = 0; n < 4; ++n) {
        A2[n] = -__expf(A_log[d * NSTATE + sub * 4 + n]) * 1.44269504f;
        h[n] = 0.f;
    }
    const float Dval = Dv[d];
    const size_t bL = (size_t)b * LSEQ;

    const float* pdt = dt + (bL + sub) * DINNER + d;
    const float* pxc = xc + (bL + sub) * DINNER + d;
    const float* pz  = xz + ((bL + sub) << 11) + DINNER + d;

    const float* xrow = xdbl + bL * 64;
    const int roff = (lane >> 4) * 64 + (lane & 15) * 4;
    float* lds0 = &sBC[w][0][0];
    float* lds1 = &sBC[w][1][0];

    float4 r0 = *(const float4*)(xrow + roff);
    float4 r1 = *(const float4*)(xrow + 256 + roff);
    float4 rowreg = *(const float4*)(xrow + 512 + roff);
    *(float4*)(lds0 + roff) = r0;
    *(float4*)(lds1 + roff) = r1;

    float dt_c = pdt[0];          float xc_c = pxc[0];          float z_c = pz[0];
    float dt_1 = pdt[4 * DINNER]; float xc_1 = pxc[4 * DINNER]; float z_1 = pz[4 * 2048];

    for (int g = 0; g < 49; ++g) {
        const int gl  = (g + 3 <= 48) ? g + 3 : 48;
        float4 rownext = *(const float4*)(xrow + gl * 256 + roff);
        const int adv = (g < 47) ? 2 : (48 - g);
        float dt_2 = pdt[(size_t)adv * 4 * DINNER];
        float xc_2 = pxc[(size_t)adv * 4 * DINNER];
        float z_2  = pz[(size_t)adv * 4 * 2048];

        const float* Bbuf = (g & 1) ? lds1 : lds0;
        float acc_keep = 0.f;

#define SCAN_STEP(J) do {                                                     \
        float4 Bv = *(const float4*)&Bbuf[(J) * 64 + 32 + 4 * sub];           \
        float4 Cv = *(const float4*)&Bbuf[(J) * 64 + 48 + 4 * sub];           \
        float dtv = qbcast<J>(dt_c);                                          \
        float xv  = qbcast<J>(xc_c);                                          \
        float dtx = dtv * xv;                                                 \
        h[0] = exp2f(dtv * A2[0]) * h[0] + dtx * Bv.x;                        \
        h[1] = exp2f(dtv * A2[1]) * h[1] + dtx * Bv.y;                        \
        h[2] = exp2f(dtv * A2[2]) * h[2] + dtx * Bv.z;                        \
        h[3] = exp2f(dtv * A2[3]) * h[3] + dtx * Bv.w;                        \
        float acc = h[0] * Cv.x + h[1] * Cv.y + h[2] * Cv.z + h[3] * Cv.w;    \
        acc += __shfl_xor(acc, 1);                                            \
        acc += __shfl_xor(acc, 2);                                            \
        acc_keep = (sub == (J)) ? acc : acc_keep;                             \
    } while (0)

        SCAN_STEP(0);
        SCAN_STEP(1);
        SCAN_STEP(2);
        SCAN_STEP(3);
#undef SCAN_STEP

        {
            float yv = acc_keep + xc_c * Dval;
            float sz = z_c * __builtin_amdgcn_rcpf(1.f + __expf(-z_c));
            float o  = yv * sz;
            bf16_t ho = (bf16_t)o;
            const size_t oi = (bL + 4 * (size_t)g + sub) * DINNER + d;
            yh[oi] = ho;
            yl[oi] = (bf16_t)(o - (float)ho);
        }

        *(float4*)(((g & 1) ? lds1 : lds0) + roff) = rowreg;
        rowreg = rownext;

        pdt += 4 * DINNER; pxc += 4 * DINNER; pz += 4 * 2048;
        dt_c = dt_1; xc_c = xc_1; z_c = z_1;
        dt_1 = dt_2; xc_1 = xc_2; z_1 = z_2;
    }
}

// ---------------------------------------------------------------------------
// Mean pool over L, then (tiny) classifier head.
// ---------------------------------------------------------------------------
__global__ __launch_bounds__(256) void pool_kernel(
    const float* __restrict__ t, float* __restrict__ pooled)
{
    int idx = blockIdx.x * 256 + threadIdx.x;   // 32*512 = 16384
    int dm = idx & (DMODEL - 1);
    int b = idx >> 9;
    float s = 0.f;
    for (int l = 0; l < LSEQ; ++l)
        s += t[((size_t)(b * LSEQ + l) << 9) + dm];
    pooled[idx] = s * (1.f / (float)LSEQ);
}

__global__ __launch_bounds__(320) void head_kernel(
    const float* __restrict__ pooled, const float* __restrict__ Wh,
    const float* __restrict__ bh, float* __restrict__ out)
{
    int tid = threadIdx.x;
    if (tid >= 320) return;
    int b = tid / 10, o = tid % 10;
    float s = bh[o];
    for (int k = 0; k < DMODEL; ++k)
        s += pooled[b * DMODEL + k] * Wh[o * DMODEL + k];
    out[b * 10 + o] = s;
}

// ---------------------------------------------------------------------------
extern "C" void kernel_launch(void* const* d_in, const int* in_sizes, int n_in,
                              void* d_out, int out_size, void* d_ws, size_t ws_size,
                              hipStream_t stream)
{
    const float* x         = (const float*)d_in[0];
    const float* ln0_g     = (const float*)d_in[1];
    const float* ln0_b     = (const float*)d_in[2];
    const float* W_emb     = (const float*)d_in[3];
    const float* b_emb     = (const float*)d_in[4];
    const float* ln1_g     = (const float*)d_in[5];
    const float* ln1_b     = (const float*)d_in[6];
    const float* in_proj_w = (const float*)d_in[7];
    const float* conv_w    = (const float*)d_in[8];
    const float* conv_b    = (const float*)d_in[9];
    const float* x_proj_w  = (const float*)d_in[10];
    const float* dt_proj_w = (const float*)d_in[11];
    const float* dt_proj_b = (const float*)d_in[12];
    const float* A_log     = (const float*)d_in[13];
    const float* D_p       = (const float*)d_in[14];
    const float* out_proj_w= (const float*)d_in[15];
    const float* blk_ln_g  = (const float*)d_in[16];
    const float* blk_ln_b  = (const float*)d_in[17];
    const float* W_head    = (const float*)d_in[18];
    const float* b_head    = (const float*)d_in[19];

    const int M = BATCHN * LSEQ;   // 6272 rows
    const int NSPLIT = 8;          // x_proj split-K factor (K=1024 -> 128)

    char* ws = (char*)d_ws;
    size_t off = 0;
    auto alloc = [&](size_t bytes) -> void* {
        void* p = (void*)(ws + off);
        off += (bytes + 255) & ~(size_t)255;
        return p;
    };
    // NOTE: workspace budget is tight (~256MB). Two aliases (stream-order
    // safe):  xdbl_p reuses tp (tp dead after the stem embedding GEMM);
    // yout reuses dtbuf (dt dead after scan; dtbuf rewritten only next layer
    // after the LN that consumes yout).
    float*  tp     = (float*)alloc((size_t)M * PDIM * 4);
    bf16_t* tp_h   = (bf16_t*)alloc((size_t)M * PDIM * 2);
    bf16_t* tp_l   = (bf16_t*)alloc((size_t)M * PDIM * 2);
    float*  t      = (float*)alloc((size_t)M * DMODEL * 4);
    bf16_t* t_h    = (bf16_t*)alloc((size_t)M * DMODEL * 2);
    bf16_t* t_l    = (bf16_t*)alloc((size_t)M * DMODEL * 2);
    float*  xz     = (float*)alloc((size_t)M * 2 * DINNER * 4);
    float*  xc     = (float*)alloc((size_t)M * DINNER * 4);
    float*  xdbl   = (float*)alloc((size_t)M * 64 * 4);
    float*  dtbuf  = (float*)alloc((size_t)M * DINNER * 4);
    bf16_t* y_h    = (bf16_t*)alloc((size_t)M * DINNER * 2);
    bf16_t* y_l    = (bf16_t*)alloc((size_t)M * DINNER * 2);
    float*  pooled = (float*)alloc((size_t)BATCHN * DMODEL * 4);
    float*  xdbl_p = tp;       // alias: NSPLIT*M*64*4 = 12.8MB <= 19.3MB
    float*  yout   = dtbuf;    // alias: 2*M*DMODEL*4 = 25.7MB == dtbuf size
    const int n_inW  = NLAYER * 2 * DINNER * DMODEL;   // 6,291,456
    const int n_outW = NLAYER * DMODEL * DINNER;       // 3,145,728
    const int n_embW = DMODEL * PDIM;                  // 393,216
    bf16_t* winh  = (bf16_t*)alloc((size_t)n_inW * 2);
    bf16_t* winl  = (bf16_t*)alloc((size_t)n_inW * 2);
    bf16_t* wouth = (bf16_t*)alloc((size_t)n_outW * 2);
    bf16_t* woutl = (bf16_t*)alloc((size_t)n_outW * 2);
    bf16_t* wembh = (bf16_t*)alloc((size_t)n_embW * 2);
    bf16_t* wembl = (bf16_t*)alloc((size_t)n_embW * 2);
    (void)ws_size; (void)in_sizes; (void)n_in; (void)out_size;

    // --- weight splits (hi/lo bf16) ---
    split_kernel<<<(n_inW  + 255) / 256, 256, 0, stream>>>(in_proj_w,  winh,  winl,  n_inW);
    split_kernel<<<(n_outW + 255) / 256, 256, 0, stream>>>(out_proj_w, wouth, woutl, n_outW);
    split_kernel<<<(n_embW + 255) / 256, 256, 0, stream>>>(W_emb,      wembh, wembl, n_embW);

    // --- stem ---
    patchify_kernel<<<(M * PDIM) / 256, 256, 0, stream>>>(x, tp);
    ln_kernel<<<M, 256, 0, stream>>>(tp, nullptr, nullptr, ln0_g, ln0_b,
                                     nullptr, tp_h, tp_l, PDIM);
    gemm_mfma3<<<dim3(DMODEL / 128, M / 128, 1), 256, 0, stream>>>(
        tp_h, tp_l, wembh, wembl, t, b_emb, M, DMODEL, PDIM);
    ln_kernel<<<M, 256, 0, stream>>>(t, nullptr, nullptr, ln1_g, ln1_b,
                                     t, t_h, t_l, DMODEL);

    // --- mamba layers ---
    for (int i = 0; i < NLAYER; ++i) {
        const bf16_t* winh_i  = winh  + (size_t)i * 2 * DINNER * DMODEL;
        const bf16_t* winl_i  = winl  + (size_t)i * 2 * DINNER * DMODEL;
        const bf16_t* wouth_i = wouth + (size_t)i * DMODEL * DINNER;
        const bf16_t* woutl_i = woutl + (size_t)i * DMODEL * DINNER;
        const float* cw   = conv_w    + (size_t)i * DINNER * 4;
        const float* cb   = conv_b    + (size_t)i * DINNER;
        const float* xpW  = x_proj_w  + (size_t)i * 64 * DINNER;
        const float* dtW  = dt_proj_w + (size_t)i * DINNER * RRANK;
        const float* dtB  = dt_proj_b + (size_t)i * DINNER;
        const float* Ali  = A_log     + (size_t)i * DINNER * NSTATE;
        const float* Di   = D_p       + (size_t)i * DINNER;
        const float* bg   = blk_ln_g  + (size_t)i * DMODEL;
        const float* bb   = blk_ln_b  + (size_t)i * DMODEL;

        // xz = t @ inW^T   (6272 x 2048, K=512)  [bf16x3 MFMA, A-direct]
        gemm_mfma3<<<dim3((2 * DINNER) / 128, M / 128, 1), 256, 0, stream>>>(
            t_h, t_l, winh_i, winl_i, xz, nullptr, M, 2 * DINNER, DMODEL);
        // xc = silu(conv(xs)) fused with x_proj split-K=8 partials
        conv_xproj_kernel<<<dim3(1, M / 64, NSPLIT), 256, 0, stream>>>(
            xz, cw, cb, xpW, xc, xdbl_p, DINNER / NSPLIT);
        reduce_splitk<<<(M * 64 + 255) / 256, 256, 0, stream>>>(
            xdbl_p, xdbl, M * 64, NSPLIT);
        // dt = softplus(x_dbl[:, :32] @ dtW^T + dtB)   (K=32)  [fp32 vector]
        gemm_nt<<<dim3(DINNER / 64, M / 64), 256, 0, stream>>>(
            xdbl, 64, dtW, dtbuf, DINNER, dtB, M, DINNER, RRANK, 1);
        // selective scan + D skip + silu(z); emits y as bf16 hi/lo
        scan_kernel<<<dim3(DINNER / 64, BATCHN), 256, 0, stream>>>(
            xc, dtbuf, xdbl, Ali, Di, xz, y_h, y_l);
        // yout = y @ outW^T   (6272 x 512, K=1024)  [MFMA, split-K=2]
        // (yout aliases dtbuf — dt is dead after scan_kernel)
        gemm_mfma3<<<dim3(DMODEL / 128, M / 128, 2), 256, 0, stream>>>(
            y_h, y_l, wouth_i, woutl_i, yout, nullptr, M, DMODEL, DINNER);
        // t = LN(yout0 + yout1 + t), plus hi/lo split for next in_proj
        ln_kernel<<<M, 256, 0, stream>>>(yout, yout + (size_t)M * DMODEL, t,
                                         bg, bb, t, t_h, t_l, DMODEL);
    }

    // --- pool + head ---
    pool_kernel<<<(BATCHN * DMODEL) / 256, 256, 0, stream>>>(t, pooled);
    head_kernel<<<1, 320, 0, stream>>>(pooled, W_head, b_head, (float*)d_out);
}

// Round 11
// 1561.930 us; speedup vs baseline: 1.1281x; 1.1281x over previous
//
#include <hip/hip_runtime.h>
#include <cstdint>
#include <cstddef>

// Problem constants
#define BATCHN 32
#define LSEQ   196     // (224/16)^2
#define DMODEL 512
#define DINNER 1024    // 2*DM
#define PDIM   768     // 3*16*16
#define NSTATE 16
#define RRANK  32
#define NLAYER 6

typedef __bf16 bf16_t;
typedef __bf16 bf16x8 __attribute__((ext_vector_type(8)));
typedef float  f32x4  __attribute__((ext_vector_type(4)));

// async global->LDS, 16B per lane: lane i lands at lds + i*16 bytes.
__device__ __forceinline__ void gl_lds16(const bf16_t* g, bf16_t* l) {
    __builtin_amdgcn_global_load_lds(
        (const __attribute__((address_space(1))) void*)g,
        (__attribute__((address_space(3))) void*)l, 16, 0, 0);
}

// A-side activations are stored FRAGMENT-MAJOR ("swizzled"): for each
// 16-row x 32-col K-panel, the 64 lane-fragments (16B each) are contiguous:
//   addr(row,c) = ((row>>4)*KT + (c>>5))*512
//               + ((row&15) | ((c>>3)&3)<<4)*8 + (c&7),  KT = K/32.
// This makes the GEMM's A-fragment load ONE coalesced dwordx4 per (mt,ki)
// with lane L holding row L&15, k-chunk L>>4 (the MFMA A-mapping).
__device__ __forceinline__ size_t swz_addr(int row, int c, int KT) {
    return (((size_t)(row >> 4) * KT + (c >> 5)) << 9)
         + (((row & 15) | (((c >> 3) & 3) << 4)) << 3) + (c & 7);
}

// ---------------------------------------------------------------------------
// Split fp32 -> (hi, lo) bf16 pair (weights; row-major, B-side).
// ---------------------------------------------------------------------------
__global__ __launch_bounds__(256) void split_kernel(
    const float* __restrict__ src, bf16_t* __restrict__ hi,
    bf16_t* __restrict__ lo, int n)
{
    int i = blockIdx.x * 256 + threadIdx.x;
    if (i < n) {
        float x = src[i];
        bf16_t h = (bf16_t)x;
        hi[i] = h;
        lo[i] = (bf16_t)(x - (float)h);
    }
}

// ---------------------------------------------------------------------------
// bf16x3 split-precision MFMA GEMM:  C = A[M,K] @ W[N,K]^T (+bias)
// A (hi/lo) in fragment-major swizzled layout -> direct coalesced
// global->VGPR loads (A never touches LDS).  B staged via gl_lds,
// double-buffered; one barrier per K-iter (R10 structure, now with
// coalesced A).  LDS/iter: 48KB vs 96KB of the all-LDS version -> LDS-BW
// ceiling on MfmaUtil rises ~27% -> ~55%.
// Split-K via gridDim.z: partials to C + z*M*N (summed by the next LN).
// Requires M%128==0, N%128==0, (K/gridDim.z)%32==0.
// ---------------------------------------------------------------------------
__global__ __launch_bounds__(256) void gemm_mfma3(
    const bf16_t* __restrict__ Ah, const bf16_t* __restrict__ Al,
    const bf16_t* __restrict__ Wh, const bf16_t* __restrict__ Wl,
    float* __restrict__ C, const float* __restrict__ bias,
    int M, int N, int K)
{
    __shared__ bf16_t sBh[2][128 * 32];
    __shared__ bf16_t sBl[2][128 * 32];

    const int bm = blockIdx.y * 128;
    const int bn = blockIdx.x * 128;
    const int kchunk = K / gridDim.z;
    const int kb = blockIdx.z * kchunk;
    const int KT = K >> 5;
    C += (size_t)blockIdx.z * M * N;

    const int tid  = threadIdx.x;
    const int lane = tid & 63;
    const int w    = tid >> 6;
    const int wm   = (w & 1) * 64;
    const int wn   = (w >> 1) * 64;

    // B staging (gl_lds 16B/lane), XOR-swizzled source chunks.
    const int lrow = lane >> 2;
    const int cg8  = ((lane & 3) ^ ((lane >> 3) & 3)) * 8;
    const size_t brow = (size_t)(bn + w * 32 + lrow) * K + cg8;
    const int llo = w * 1024;

    const int fr  = lane & 15;
    const int fsw = ((lane >> 4) ^ ((lane >> 1) & 3)) * 8;

    // A: swizzled panel base.  Panel (rt, kt) occupies 512 elems.
    const size_t abase = ((size_t)((bm + wm) >> 4) * KT + (kb >> 5)) * 512
                       + (size_t)lane * 8;
    const size_t amt = (size_t)KT * 512;   // stride between mt row-tiles

    f32x4 acc[4][4] = {};

    // prologue: stage B tile 0, load A frags 0 (coalesced)
    #pragma unroll
    for (int j = 0; j < 2; ++j) {
        gl_lds16(Wh + brow + (size_t)j * 16 * K + kb, &sBh[0][llo + j * 512]);
        gl_lds16(Wl + brow + (size_t)j * 16 * K + kb, &sBl[0][llo + j * 512]);
    }
    bf16x8 afh[4], afl[4];
    #pragma unroll
    for (int mt = 0; mt < 4; ++mt) {
        afh[mt] = *(const bf16x8*)(Ah + abase + (size_t)mt * amt);
        afl[mt] = *(const bf16x8*)(Al + abase + (size_t)mt * amt);
    }

    const int kiter = kchunk / 32;
    for (int ki = 0; ki < kiter; ++ki) {
        const int buf = ki & 1;
        __syncthreads();   // B[ki] staged (vmcnt0 drain also retires A[ki])

        // prefetch next tile: A -> regs (coalesced), B -> other LDS buffer
        bf16x8 nfh[4], nfl[4];
        if (ki + 1 < kiter) {
            const size_t ab = abase + (size_t)(ki + 1) * 512;
            #pragma unroll
            for (int mt = 0; mt < 4; ++mt) {
                nfh[mt] = *(const bf16x8*)(Ah + ab + (size_t)mt * amt);
                nfl[mt] = *(const bf16x8*)(Al + ab + (size_t)mt * amt);
            }
            const int k0 = kb + (ki + 1) * 32;
            #pragma unroll
            for (int j = 0; j < 2; ++j) {
                gl_lds16(Wh + brow + (size_t)j * 16 * K + k0,
                         &sBh[buf ^ 1][llo + j * 512]);
                gl_lds16(Wl + brow + (size_t)j * 16 * K + k0,
                         &sBl[buf ^ 1][llo + j * 512]);
            }
        }

        // MFMA sweep; B fragments read inline from the stable sB[buf]
        #pragma unroll
        for (int nt = 0; nt < 4; ++nt) {
            const int r = wn + nt * 16 + fr;
            bf16x8 bfh = *(const bf16x8*)&sBh[buf][r * 32 + fsw];
            bf16x8 bfl = *(const bf16x8*)&sBl[buf][r * 32 + fsw];
            #pragma unroll
            for (int mt = 0; mt < 4; ++mt)
                acc[mt][nt] = __builtin_amdgcn_mfma_f32_16x16x32_bf16(
                    afh[mt], bfh, acc[mt][nt], 0, 0, 0);
            #pragma unroll
            for (int mt = 0; mt < 4; ++mt)
                acc[mt][nt] = __builtin_amdgcn_mfma_f32_16x16x32_bf16(
                    afh[mt], bfl, acc[mt][nt], 0, 0, 0);
            #pragma unroll
            for (int mt = 0; mt < 4; ++mt)
                acc[mt][nt] = __builtin_amdgcn_mfma_f32_16x16x32_bf16(
                    afl[mt], bfh, acc[mt][nt], 0, 0, 0);
        }

        if (ki + 1 < kiter) {
            #pragma unroll
            for (int mt = 0; mt < 4; ++mt) {
                afh[mt] = nfh[mt]; afl[mt] = nfl[mt];
            }
        }
    }

    // epilogue: C/D layout col=lane&15, row=(lane>>4)*4+reg  [m89-verified]
    const int cr = (lane >> 4) * 4;
    const int cc = lane & 15;
    #pragma unroll
    for (int nt = 0; nt < 4; ++nt) {
        const int n = bn + wn + nt * 16 + cc;
        const float bv = bias ? bias[n] : 0.f;
        #pragma unroll
        for (int mt = 0; mt < 4; ++mt) {
            const int m0 = bm + wm + mt * 16 + cr;
            #pragma unroll
            for (int r = 0; r < 4; ++r)
                C[(size_t)(m0 + r) * N + n] = acc[mt][nt][r] + bv;
        }
    }
}

// ---------------------------------------------------------------------------
// fp32 vector NT GEMM (used for dt_proj: K=32).  C = A@W^T (+bias)(+softplus)
// ---------------------------------------------------------------------------
__global__ __launch_bounds__(256) void gemm_nt(
    const float* __restrict__ A, int lda,
    const float* __restrict__ W,
    float* __restrict__ C, int ldc,
    const float* __restrict__ bias,
    int M, int N, int K, int act)
{
    __shared__ float As[16][64];
    __shared__ float Ws[16][64];
    const int bm = blockIdx.y * 64;
    const int bn = blockIdx.x * 64;
    const int tid = threadIdx.x;
    const int tx = tid & 15;
    const int ty = tid >> 4;
    const int r   = tid >> 2;
    const int kk4 = (tid & 3) << 2;

    float acc[4][4];
    #pragma unroll
    for (int i = 0; i < 4; ++i)
        #pragma unroll
        for (int j = 0; j < 4; ++j) acc[i][j] = 0.f;

    for (int k0 = 0; k0 < K; k0 += 16) {
        float4 va = *(const float4*)(A + (size_t)(bm + r) * lda + k0 + kk4);
        float4 vw = *(const float4*)(W + (size_t)(bn + r) * K   + k0 + kk4);
        __syncthreads();
        As[kk4 + 0][r] = va.x; As[kk4 + 1][r] = va.y;
        As[kk4 + 2][r] = va.z; As[kk4 + 3][r] = va.w;
        Ws[kk4 + 0][r] = vw.x; Ws[kk4 + 1][r] = vw.y;
        Ws[kk4 + 2][r] = vw.z; Ws[kk4 + 3][r] = vw.w;
        __syncthreads();
        #pragma unroll
        for (int kk = 0; kk < 16; ++kk) {
            float4 a = *(const float4*)&As[kk][ty << 2];
            float4 b = *(const float4*)&Ws[kk][tx << 2];
            acc[0][0] += a.x * b.x; acc[0][1] += a.x * b.y;
            acc[0][2] += a.x * b.z; acc[0][3] += a.x * b.w;
            acc[1][0] += a.y * b.x; acc[1][1] += a.y * b.y;
            acc[1][2] += a.y * b.z; acc[1][3] += a.y * b.w;
            acc[2][0] += a.z * b.x; acc[2][1] += a.z * b.y;
            acc[2][2] += a.z * b.z; acc[2][3] += a.z * b.w;
            acc[3][0] += a.w * b.x; acc[3][1] += a.w * b.y;
            acc[3][2] += a.w * b.z; acc[3][3] += a.w * b.w;
        }
    }

    #pragma unroll
    for (int i = 0; i < 4; ++i) {
        const int m = bm + (ty << 2) + i;
        #pragma unroll
        for (int j = 0; j < 4; ++j) {
            const int n = bn + (tx << 2) + j;
            float v = acc[i][j];
            if (bias) v += bias[n];
            if (act == 1) {
                v = (v > 20.f) ? v : log1pf(expf(v));
            }
            C[(size_t)m * ldc + n] = v;
        }
    }
}

// ---------------------------------------------------------------------------
// FUSED conv+silu+x_proj split-K.  grid=(1, M/64, NSPLIT).
// ---------------------------------------------------------------------------
__global__ __launch_bounds__(256) void conv_xproj_kernel(
    const float* __restrict__ xz, const float* __restrict__ cw,
    const float* __restrict__ cb, const float* __restrict__ xpW,
    float* __restrict__ xc, float* __restrict__ Cpart,
    int kchunk)
{
    __shared__ float As[16][64];
    __shared__ float Ws[16][64];
    __shared__ float scw[128 * 4 + 128];   // conv w (128 ch x 4) + bias (128)

    const int bm = blockIdx.y * 64;
    const int kb = blockIdx.z * kchunk;
    Cpart += (size_t)blockIdx.z * (BATCHN * LSEQ) * 64;

    const int tid = threadIdx.x;
    if (tid < 128) {
        *(float4*)&scw[tid * 4] = *(const float4*)(cw + (size_t)(kb + tid) * 4);
        scw[512 + tid] = cb[kb + tid];
    }
    __syncthreads();

    const int tx = tid & 15;
    const int ty = tid >> 4;
    const int r   = tid >> 2;
    const int kk4 = (tid & 3) << 2;
    const int bl  = bm + r;          // global token row
    const int l   = bl % LSEQ;       // position within batch
    const float* xrow = xz + ((size_t)bl << 11);   // xs row (stride 2048)

    float acc[4][4];
    #pragma unroll
    for (int i = 0; i < 4; ++i)
        #pragma unroll
        for (int j = 0; j < 4; ++j) acc[i][j] = 0.f;

    for (int k0 = 0; k0 < kchunk; k0 += 16) {
        const int cl = k0 + kk4;       // channel offset within split
        const int c  = kb + cl;        // global channel
        float4 va = *(const float4*)&scw[512 + cl];
        #pragma unroll
        for (int kk = 0; kk < 4; ++kk) {
            int ls = l + kk - 3;
            if (ls >= 0) {
                float4 xv = *(const float4*)(xrow + ((ptrdiff_t)(kk - 3) << 11) + c);
                va.x += scw[(cl + 0) * 4 + kk] * xv.x;
                va.y += scw[(cl + 1) * 4 + kk] * xv.y;
                va.z += scw[(cl + 2) * 4 + kk] * xv.z;
                va.w += scw[(cl + 3) * 4 + kk] * xv.w;
            }
        }
        va.x = va.x * __builtin_amdgcn_rcpf(1.f + __expf(-va.x));
        va.y = va.y * __builtin_amdgcn_rcpf(1.f + __expf(-va.y));
        va.z = va.z * __builtin_amdgcn_rcpf(1.f + __expf(-va.z));
        va.w = va.w * __builtin_amdgcn_rcpf(1.f + __expf(-va.w));
        *(float4*)(xc + ((size_t)bl << 10) + c) = va;

        float4 vw = *(const float4*)(xpW + (size_t)r * DINNER + c);
        __syncthreads();
        As[kk4 + 0][r] = va.x; As[kk4 + 1][r] = va.y;
        As[kk4 + 2][r] = va.z; As[kk4 + 3][r] = va.w;
        Ws[kk4 + 0][r] = vw.x; Ws[kk4 + 1][r] = vw.y;
        Ws[kk4 + 2][r] = vw.z; Ws[kk4 + 3][r] = vw.w;
        __syncthreads();
        #pragma unroll
        for (int kk = 0; kk < 16; ++kk) {
            float4 a = *(const float4*)&As[kk][ty << 2];
            float4 b = *(const float4*)&Ws[kk][tx << 2];
            acc[0][0] += a.x * b.x; acc[0][1] += a.x * b.y;
            acc[0][2] += a.x * b.z; acc[0][3] += a.x * b.w;
            acc[1][0] += a.y * b.x; acc[1][1] += a.y * b.y;
            acc[1][2] += a.y * b.z; acc[1][3] += a.y * b.w;
            acc[2][0] += a.z * b.x; acc[2][1] += a.z * b.y;
            acc[2][2] += a.z * b.z; acc[2][3] += a.z * b.w;
            acc[3][0] += a.w * b.x; acc[3][1] += a.w * b.y;
            acc[3][2] += a.w * b.z; acc[3][3] += a.w * b.w;
        }
    }

    #pragma unroll
    for (int i = 0; i < 4; ++i) {
        const int m = bm + (ty << 2) + i;
        #pragma unroll
        for (int j = 0; j < 4; ++j) {
            const int n = (tx << 2) + j;
            Cpart[(size_t)m * 64 + n] = acc[i][j];
        }
    }
}

__global__ __launch_bounds__(256) void reduce_splitk(
    const float* __restrict__ part, float* __restrict__ out, int n, int nsplit)
{
    int i = blockIdx.x * 256 + threadIdx.x;
    if (i < n) {
        float s = 0.f;
        for (int j = 0; j < nsplit; ++j) s += part[(size_t)j * n + i];
        out[i] = s;
    }
}

// ---------------------------------------------------------------------------
// Patchify: x (B,3,224,224) -> tp (B, 196, 768), pd = c*256 + p1*16 + p2
// ---------------------------------------------------------------------------
__global__ __launch_bounds__(256) void patchify_kernel(
    const float* __restrict__ x, float* __restrict__ tp)
{
    int idx = blockIdx.x * 256 + threadIdx.x;   // B*L*PD = 4,816,896
    int pd = idx % PDIM;
    int bl = idx / PDIM;
    int l = bl % LSEQ, b = bl / LSEQ;
    int c = pd >> 8, rem = pd & 255, p1 = rem >> 4, p2 = rem & 15;
    int gh = l / 14, gw = l % 14;
    int hh = gh * 16 + p1, ww = gw * 16 + p2;
    tp[idx] = x[(((size_t)b * 3 + c) * 224 + hh) * 224 + ww];
}

// ---------------------------------------------------------------------------
// LayerNorm over last dim W (512 or 768). Optional second input (split-K
// partial sum), optional residual, optional fp32 out, optional bf16 hi/lo
// (hi/lo emitted in the SWIZZLED fragment-major layout for the MFMA GEMM).
// ---------------------------------------------------------------------------
__global__ __launch_bounds__(256) void ln_kernel(
    const float* __restrict__ in, const float* __restrict__ in2,
    const float* __restrict__ res,
    const float* __restrict__ g, const float* __restrict__ bt,
    float* __restrict__ out, bf16_t* __restrict__ hi,
    bf16_t* __restrict__ lo, int W)
{
    __shared__ float red[4];
    const int row = blockIdx.x;
    const size_t base = (size_t)row * W;
    const int nper = W >> 8;      // 2 or 3
    const int KT = W >> 5;
    float vals[3];
    float s = 0.f;
    for (int j = 0; j < nper; ++j) {
        int c = (j << 8) + threadIdx.x;
        float v = in[base + c];
        if (in2) v += in2[base + c];
        if (res) v += res[base + c];
        vals[j] = v;
        s += v;
    }
    int lane = threadIdx.x & 63, wid = threadIdx.x >> 6;
    #pragma unroll
    for (int o = 32; o > 0; o >>= 1) s += __shfl_down(s, o);
    if (lane == 0) red[wid] = s;
    __syncthreads();
    float mu = (red[0] + red[1] + red[2] + red[3]) / (float)W;
    __syncthreads();
    float vs = 0.f;
    for (int j = 0; j < nper; ++j) { float d = vals[j] - mu; vs += d * d; }
    #pragma unroll
    for (int o = 32; o > 0; o >>= 1) vs += __shfl_down(vs, o);
    if (lane == 0) red[wid] = vs;
    __syncthreads();
    float var = (red[0] + red[1] + red[2] + red[3]) / (float)W;
    float rstd = rsqrtf(var + 1e-5f);
    for (int j = 0; j < nper; ++j) {
        int c = (j << 8) + threadIdx.x;
        float v = (vals[j] - mu) * rstd * g[c] + bt[c];
        if (out) out[base + c] = v;
        if (hi) {
            bf16_t h = (bf16_t)v;
            const size_t a = swz_addr(row, c, KT);
            hi[a] = h;
            lo[a] = (bf16_t)(v - (float)h);
        }
    }
}

// ---------------------------------------------------------------------------
// quad broadcast: all 4 lanes of a quad get lane J's value (DPP quad_perm).
// ---------------------------------------------------------------------------
template<int J>
__device__ __forceinline__ float qbcast(float v) {
    constexpr int ctrl = J | (J << 2) | (J << 4) | (J << 6);
    return __int_as_float(__builtin_amdgcn_mov_dpp(
        __float_as_int(v), ctrl, 0xF, 0xF, true));
}

// ---------------------------------------------------------------------------
// Selective scan v6: state-parallel, group-4 steps, wave-private LDS staging
// of shared B/C rows, depth-2 scalar pipeline, group-batched stores.
// y emitted as bf16 hi/lo in the SWIZZLED fragment-major layout (KT=32).
// ---------------------------------------------------------------------------
__global__ __launch_bounds__(256, 1) void scan_kernel(
    const float* __restrict__ xc, const float* __restrict__ dt,
    const float* __restrict__ xdbl, const float* __restrict__ A_log,
    const float* __restrict__ Dv, const float* __restrict__ xz,
    bf16_t* __restrict__ yh, bf16_t* __restrict__ yl)
{
    __shared__ float sBC[4][2][256];   // [wave][buf][4 steps x 64 floats]

    const int b    = blockIdx.y;
    const int tid  = threadIdx.x;
    const int lane = tid & 63;
    const int w    = tid >> 6;
    const int q    = tid >> 2;        // channel within block (0..63)
    const int sub  = tid & 3;         // state group: states [4*sub, 4*sub+4)
    const int d    = blockIdx.x * 64 + q;

    float A2[4], h[4];
    #pragma unroll
    for (int n = 0; n < 4; ++n) {
        A2[n] = -__expf(A_log[d * NSTATE + sub * 4 + n]) * 1.44269504f;
        h[n] = 0.f;
    }
    const float Dval = Dv[d];
    const size_t bL = (size_t)b * LSEQ;

    const float* pdt = dt + (bL + sub) * DINNER + d;
    const float* pxc = xc + (bL + sub) * DINNER + d;
    const float* pz  = xz + ((bL + sub) << 11) + DINNER + d;

    const float* xrow = xdbl + bL * 64;
    const int roff = (lane >> 4) * 64 + (lane & 15) * 4;
    float* lds0 = &sBC[w][0][0];
    float* lds1 = &sBC[w][1][0];

    float4 r0 = *(const float4*)(xrow + roff);
    float4 r1 = *(const float4*)(xrow + 256 + roff);
    float4 rowreg = *(const float4*)(xrow + 512 + roff);
    *(float4*)(lds0 + roff) = r0;
    *(float4*)(lds1 + roff) = r1;

    float dt_c = pdt[0];          float xc_c = pxc[0];          float z_c = pz[0];
    float dt_1 = pdt[4 * DINNER]; float xc_1 = pxc[4 * DINNER]; float z_1 = pz[4 * 2048];

    for (int g = 0; g < 49; ++g) {
        const int gl  = (g + 3 <= 48) ? g + 3 : 48;
        float4 rownext = *(const float4*)(xrow + gl * 256 + roff);
        const int adv = (g < 47) ? 2 : (48 - g);
        float dt_2 = pdt[(size_t)adv * 4 * DINNER];
        float xc_2 = pxc[(size_t)adv * 4 * DINNER];
        float z_2  = pz[(size_t)adv * 4 * 2048];

        const float* Bbuf = (g & 1) ? lds1 : lds0;
        float acc_keep = 0.f;

#define SCAN_STEP(J) do {                                                     \
        float4 Bv = *(const float4*)&Bbuf[(J) * 64 + 32 + 4 * sub];           \
        float4 Cv = *(const float4*)&Bbuf[(J) * 64 + 48 + 4 * sub];           \
        float dtv = qbcast<J>(dt_c);                                          \
        float xv  = qbcast<J>(xc_c);                                          \
        float dtx = dtv * xv;                                                 \
        h[0] = exp2f(dtv * A2[0]) * h[0] + dtx * Bv.x;                        \
        h[1] = exp2f(dtv * A2[1]) * h[1] + dtx * Bv.y;                        \
        h[2] = exp2f(dtv * A2[2]) * h[2] + dtx * Bv.z;                        \
        h[3] = exp2f(dtv * A2[3]) * h[3] + dtx * Bv.w;                        \
        float acc = h[0] * Cv.x + h[1] * Cv.y + h[2] * Cv.z + h[3] * Cv.w;    \
        acc += __shfl_xor(acc, 1);                                            \
        acc += __shfl_xor(acc, 2);                                            \
        acc_keep = (sub == (J)) ? acc : acc_keep;                             \
    } while (0)

        SCAN_STEP(0);
        SCAN_STEP(1);
        SCAN_STEP(2);
        SCAN_STEP(3);
#undef SCAN_STEP

        {
            float yv = acc_keep + xc_c * Dval;
            float sz = z_c * __builtin_amdgcn_rcpf(1.f + __expf(-z_c));
            float o  = yv * sz;
            bf16_t ho = (bf16_t)o;
            const int row = (int)bL + 4 * g + sub;
            const size_t oi = swz_addr(row, d, DINNER >> 5);
            yh[oi] = ho;
            yl[oi] = (bf16_t)(o - (float)ho);
        }

        *(float4*)(((g & 1) ? lds1 : lds0) + roff) = rowreg;
        rowreg = rownext;

        pdt += 4 * DINNER; pxc += 4 * DINNER; pz += 4 * 2048;
        dt_c = dt_1; xc_c = xc_1; z_c = z_1;
        dt_1 = dt_2; xc_1 = xc_2; z_1 = z_2;
    }
}

// ---------------------------------------------------------------------------
// Mean pool over L, then (tiny) classifier head.
// ---------------------------------------------------------------------------
__global__ __launch_bounds__(256) void pool_kernel(
    const float* __restrict__ t, float* __restrict__ pooled)
{
    int idx = blockIdx.x * 256 + threadIdx.x;   // 32*512 = 16384
    int dm = idx & (DMODEL - 1);
    int b = idx >> 9;
    float s = 0.f;
    for (int l = 0; l < LSEQ; ++l)
        s += t[((size_t)(b * LSEQ + l) << 9) + dm];
    pooled[idx] = s * (1.f / (float)LSEQ);
}

__global__ __launch_bounds__(320) void head_kernel(
    const float* __restrict__ pooled, const float* __restrict__ Wh,
    const float* __restrict__ bh, float* __restrict__ out)
{
    int tid = threadIdx.x;
    if (tid >= 320) return;
    int b = tid / 10, o = tid % 10;
    float s = bh[o];
    for (int k = 0; k < DMODEL; ++k)
        s += pooled[b * DMODEL + k] * Wh[o * DMODEL + k];
    out[b * 10 + o] = s;
}

// ---------------------------------------------------------------------------
extern "C" void kernel_launch(void* const* d_in, const int* in_sizes, int n_in,
                              void* d_out, int out_size, void* d_ws, size_t ws_size,
                              hipStream_t stream)
{
    const float* x         = (const float*)d_in[0];
    const float* ln0_g     = (const float*)d_in[1];
    const float* ln0_b     = (const float*)d_in[2];
    const float* W_emb     = (const float*)d_in[3];
    const float* b_emb     = (const float*)d_in[4];
    const float* ln1_g     = (const float*)d_in[5];
    const float* ln1_b     = (const float*)d_in[6];
    const float* in_proj_w = (const float*)d_in[7];
    const float* conv_w    = (const float*)d_in[8];
    const float* conv_b    = (const float*)d_in[9];
    const float* x_proj_w  = (const float*)d_in[10];
    const float* dt_proj_w = (const float*)d_in[11];
    const float* dt_proj_b = (const float*)d_in[12];
    const float* A_log     = (const float*)d_in[13];
    const float* D_p       = (const float*)d_in[14];
    const float* out_proj_w= (const float*)d_in[15];
    const float* blk_ln_g  = (const float*)d_in[16];
    const float* blk_ln_b  = (const float*)d_in[17];
    const float* W_head    = (const float*)d_in[18];
    const float* b_head    = (const float*)d_in[19];

    const int M = BATCHN * LSEQ;   // 6272 rows
    const int NSPLIT = 8;          // x_proj split-K factor (K=1024 -> 128)

    char* ws = (char*)d_ws;
    size_t off = 0;
    auto alloc = [&](size_t bytes) -> void* {
        void* p = (void*)(ws + off);
        off += (bytes + 255) & ~(size_t)255;
        return p;
    };
    // NOTE: workspace budget is tight (~256MB). Two aliases (stream-order
    // safe):  xdbl_p reuses tp (tp dead after the stem embedding GEMM);
    // yout reuses dtbuf (dt dead after scan; dtbuf rewritten only next layer
    // after the LN that consumes yout).
    float*  tp     = (float*)alloc((size_t)M * PDIM * 4);
    bf16_t* tp_h   = (bf16_t*)alloc((size_t)M * PDIM * 2);
    bf16_t* tp_l   = (bf16_t*)alloc((size_t)M * PDIM * 2);
    float*  t      = (float*)alloc((size_t)M * DMODEL * 4);
    bf16_t* t_h    = (bf16_t*)alloc((size_t)M * DMODEL * 2);
    bf16_t* t_l    = (bf16_t*)alloc((size_t)M * DMODEL * 2);
    float*  xz     = (float*)alloc((size_t)M * 2 * DINNER * 4);
    float*  xc     = (float*)alloc((size_t)M * DINNER * 4);
    float*  xdbl   = (float*)alloc((size_t)M * 64 * 4);
    float*  dtbuf  = (float*)alloc((size_t)M * DINNER * 4);
    bf16_t* y_h    = (bf16_t*)alloc((size_t)M * DINNER * 2);
    bf16_t* y_l    = (bf16_t*)alloc((size_t)M * DINNER * 2);
    float*  pooled = (float*)alloc((size_t)BATCHN * DMODEL * 4);
    float*  xdbl_p = tp;       // alias: NSPLIT*M*64*4 = 12.8MB <= 19.3MB
    float*  yout   = dtbuf;    // alias: 2*M*DMODEL*4 = 25.7MB == dtbuf size
    const int n_inW  = NLAYER * 2 * DINNER * DMODEL;   // 6,291,456
    const int n_outW = NLAYER * DMODEL * DINNER;       // 3,145,728
    const int n_embW = DMODEL * PDIM;                  // 393,216
    bf16_t* winh  = (bf16_t*)alloc((size_t)n_inW * 2);
    bf16_t* winl  = (bf16_t*)alloc((size_t)n_inW * 2);
    bf16_t* wouth = (bf16_t*)alloc((size_t)n_outW * 2);
    bf16_t* woutl = (bf16_t*)alloc((size_t)n_outW * 2);
    bf16_t* wembh = (bf16_t*)alloc((size_t)n_embW * 2);
    bf16_t* wembl = (bf16_t*)alloc((size_t)n_embW * 2);
    (void)ws_size; (void)in_sizes; (void)n_in; (void)out_size;

    // --- weight splits (hi/lo bf16, row-major B-side) ---
    split_kernel<<<(n_inW  + 255) / 256, 256, 0, stream>>>(in_proj_w,  winh,  winl,  n_inW);
    split_kernel<<<(n_outW + 255) / 256, 256, 0, stream>>>(out_proj_w, wouth, woutl, n_outW);
    split_kernel<<<(n_embW + 255) / 256, 256, 0, stream>>>(W_emb,      wembh, wembl, n_embW);

    // --- stem ---
    patchify_kernel<<<(M * PDIM) / 256, 256, 0, stream>>>(x, tp);
    ln_kernel<<<M, 256, 0, stream>>>(tp, nullptr, nullptr, ln0_g, ln0_b,
                                     nullptr, tp_h, tp_l, PDIM);
    gemm_mfma3<<<dim3(DMODEL / 128, M / 128, 1), 256, 0, stream>>>(
        tp_h, tp_l, wembh, wembl, t, b_emb, M, DMODEL, PDIM);
    ln_kernel<<<M, 256, 0, stream>>>(t, nullptr, nullptr, ln1_g, ln1_b,
                                     t, t_h, t_l, DMODEL);

    // --- mamba layers ---
    for (int i = 0; i < NLAYER; ++i) {
        const bf16_t* winh_i  = winh  + (size_t)i * 2 * DINNER * DMODEL;
        const bf16_t* winl_i  = winl  + (size_t)i * 2 * DINNER * DMODEL;
        const bf16_t* wouth_i = wouth + (size_t)i * DMODEL * DINNER;
        const bf16_t* woutl_i = woutl + (size_t)i * DMODEL * DINNER;
        const float* cw   = conv_w    + (size_t)i * DINNER * 4;
        const float* cb   = conv_b    + (size_t)i * DINNER;
        const float* xpW  = x_proj_w  + (size_t)i * 64 * DINNER;
        const float* dtW  = dt_proj_w + (size_t)i * DINNER * RRANK;
        const float* dtB  = dt_proj_b + (size_t)i * DINNER;
        const float* Ali  = A_log     + (size_t)i * DINNER * NSTATE;
        const float* Di   = D_p       + (size_t)i * DINNER;
        const float* bg   = blk_ln_g  + (size_t)i * DMODEL;
        const float* bb   = blk_ln_b  + (size_t)i * DMODEL;

        // xz = t @ inW^T   (6272 x 2048, K=512)  [bf16x3 MFMA, swizzled A]
        gemm_mfma3<<<dim3((2 * DINNER) / 128, M / 128, 1), 256, 0, stream>>>(
            t_h, t_l, winh_i, winl_i, xz, nullptr, M, 2 * DINNER, DMODEL);
        // xc = silu(conv(xs)) fused with x_proj split-K=8 partials
        conv_xproj_kernel<<<dim3(1, M / 64, NSPLIT), 256, 0, stream>>>(
            xz, cw, cb, xpW, xc, xdbl_p, DINNER / NSPLIT);
        reduce_splitk<<<(M * 64 + 255) / 256, 256, 0, stream>>>(
            xdbl_p, xdbl, M * 64, NSPLIT);
        // dt = softplus(x_dbl[:, :32] @ dtW^T + dtB)   (K=32)  [fp32 vector]
        gemm_nt<<<dim3(DINNER / 64, M / 64), 256, 0, stream>>>(
            xdbl, 64, dtW, dtbuf, DINNER, dtB, M, DINNER, RRANK, 1);
        // selective scan + D skip + silu(z); emits y as swizzled bf16 hi/lo
        scan_kernel<<<dim3(DINNER / 64, BATCHN), 256, 0, stream>>>(
            xc, dtbuf, xdbl, Ali, Di, xz, y_h, y_l);
        // yout = y @ outW^T   (6272 x 512, K=1024)  [MFMA, split-K=2]
        // (yout aliases dtbuf — dt is dead after scan_kernel)
        gemm_mfma3<<<dim3(DMODEL / 128, M / 128, 2), 256, 0, stream>>>(
            y_h, y_l, wouth_i, woutl_i, yout, nullptr, M, DMODEL, DINNER);
        // t = LN(yout0 + yout1 + t), plus hi/lo split for next in_proj
        ln_kernel<<<M, 256, 0, stream>>>(yout, yout + (size_t)M * DMODEL, t,
                                         bg, bb, t, t_h, t_l, DMODEL);
    }

    // --- pool + head ---
    pool_kernel<<<(BATCHN * DMODEL) / 256, 256, 0, stream>>>(t, pooled);
    head_kernel<<<1, 320, 0, stream>>>(pooled, W_head, b_head, (float*)d_out);
}